// Round 1
// baseline (128.617 us; speedup 1.0000x reference)
//
#include <hip/hip_runtime.h>

// Instant-NGP single-level hash grid lookup.
// x: [B,2] f32 in [0,1); table: [524288, 2] f32; out: [B,2] f32.
// idx = (c0 ^ (2654435761*c1)) & (2^19 - 1)  -- exact vs int64 ref since
// TABLE_SIZE is a power of two and corners are nonnegative.

#define RESOLUTION 1024.0f
#define TMASK 524287u
#define PI2 2654435761u

__global__ __launch_bounds__(256) void ingp_kernel(
    const float* __restrict__ x,
    const float* __restrict__ table,
    float* __restrict__ out,
    int n)
{
    int i = blockIdx.x * blockDim.x + threadIdx.x;
    if (i >= n) return;

    const float2 xv = reinterpret_cast<const float2*>(x)[i];
    float xs0 = xv.x * RESOLUTION;
    float xs1 = xv.y * RESOLUTION;
    float f0 = floorf(xs0);
    float f1 = floorf(xs1);
    unsigned c0 = (unsigned)(int)f0;
    unsigned c1 = (unsigned)(int)f1;
    float d0 = xs0 - f0;   // weight factor for offset 1 in dim0
    float d1 = xs1 - f1;
    float e0 = 1.0f - d0;  // weight factor for offset 0
    float e1 = 1.0f - d1;

    unsigned hb0 = PI2 * c1;          // dim1 offset 0
    unsigned hb1 = PI2 * (c1 + 1u);   // dim1 offset 1
    unsigned i00 = (c0        ^ hb0) & TMASK;
    unsigned i01 = (c0        ^ hb1) & TMASK;
    unsigned i10 = ((c0 + 1u) ^ hb0) & TMASK;
    unsigned i11 = ((c0 + 1u) ^ hb1) & TMASK;

    const float2* __restrict__ t2 = reinterpret_cast<const float2*>(table);
    float2 t00 = t2[i00];
    float2 t01 = t2[i01];
    float2 t10 = t2[i10];
    float2 t11 = t2[i11];

    float w00 = e0 * e1;
    float w01 = e0 * d1;
    float w10 = d0 * e1;
    float w11 = d0 * d1;

    float o0 = t00.x * w00 + t01.x * w01 + t10.x * w10 + t11.x * w11;
    float o1 = t00.y * w00 + t01.y * w01 + t10.y * w10 + t11.y * w11;

    reinterpret_cast<float2*>(out)[i] = make_float2(o0, o1);
}

extern "C" void kernel_launch(void* const* d_in, const int* in_sizes, int n_in,
                              void* d_out, int out_size, void* d_ws, size_t ws_size,
                              hipStream_t stream) {
    const float* x     = (const float*)d_in[0];
    const float* table = (const float*)d_in[1];
    float* out         = (float*)d_out;
    const int batch = in_sizes[0] / 2;  // 4194304

    const int block = 256;
    const int grid = (batch + block - 1) / block;
    ingp_kernel<<<grid, block, 0, stream>>>(x, table, out, batch);
}